// Round 2
// baseline (12601.431 us; speedup 1.0000x reference)
//
#include <hip/hip_runtime.h>
#include <cstdint>
#include <cstddef>

#define S_LEN 512
#define TCH   128
#define NCH   4
#define HDIM  128
#define G4    512
#define BATCH 256
#define NLAYER 10

__device__ __forceinline__ float fsig(float x) {
  return __builtin_amdgcn_rcpf(1.0f + __expf(-x));
}
__device__ __forceinline__ float ftanh(float x) {
  return fmaf(2.0f, __builtin_amdgcn_rcpf(1.0f + __expf(-2.0f * x)), -1.0f);
}

// ---------------------------------------------------------------------------
// Input-projection GEMM: XG[b][tt][g] = A[b, t0+tt, :] . W[g,:] + bih[g] + bhh[g]
// (unchanged from round 1: ~64 us/dispatch, ~43% of fp32 vector peak)
// ---------------------------------------------------------------------------
template<int K>
__global__ __launch_bounds__(256, 4)
void gemm_xg(const float* __restrict__ A, const float* __restrict__ W,
             const float* __restrict__ bih, const float* __restrict__ bhh,
             float* __restrict__ XG, int t0)
{
  constexpr int BK  = (K < 64) ? K : 64;
  constexpr int NKC = K / BK;
  __shared__ float As[BK][68];
  __shared__ float Bs[BK][68];
  const int tid = threadIdx.x;
  const int tx = tid & 15;
  const int ty = tid >> 4;
  const int rowBase = blockIdx.x * 64;
  const int colBase = blockIdx.y * 64;
  float acc[4][4] = {{0.f,0.f,0.f,0.f},{0.f,0.f,0.f,0.f},{0.f,0.f,0.f,0.f},{0.f,0.f,0.f,0.f}};

  for (int kc = 0; kc < NKC; ++kc) {
    const int kbase = kc * BK;
    for (int idx = tid; idx < 64 * BK; idx += 256) {
      int rr = idx / BK;
      int k  = idx - rr * BK;
      int r  = rowBase + rr;
      int bb = r >> 7;
      int tt = r & (TCH - 1);
      As[k][rr] = A[(size_t)(bb * S_LEN + t0 + tt) * K + kbase + k];
    }
    for (int idx = tid; idx < 64 * BK; idx += 256) {
      int cc = idx / BK;
      int k  = idx - cc * BK;
      Bs[k][cc] = W[(size_t)(colBase + cc) * K + kbase + k];
    }
    __syncthreads();
    #pragma unroll 8
    for (int k = 0; k < BK; ++k) {
      const float4 av = *(const float4*)&As[k][ty * 4];
      const float4 bv = *(const float4*)&Bs[k][tx * 4];
      float a_[4] = {av.x, av.y, av.z, av.w};
      float b_[4] = {bv.x, bv.y, bv.z, bv.w};
      #pragma unroll
      for (int i = 0; i < 4; ++i) {
        #pragma unroll
        for (int jj = 0; jj < 4; ++jj)
          acc[i][jj] = fmaf(a_[i], b_[jj], acc[i][jj]);
      }
    }
    __syncthreads();
  }

  const int col0 = colBase + tx * 4;
  const float4 bi4 = *(const float4*)&bih[col0];
  const float4 bh4 = *(const float4*)&bhh[col0];
  const float b0 = bi4.x + bh4.x, b1 = bi4.y + bh4.y, b2 = bi4.z + bh4.z, b3 = bi4.w + bh4.w;
  #pragma unroll
  for (int i = 0; i < 4; ++i) {
    int r  = rowBase + ty * 4 + i;
    int bb = r >> 7;
    int tt = r & (TCH - 1);
    float4 o;
    o.x = acc[i][0] + b0; o.y = acc[i][1] + b1; o.z = acc[i][2] + b2; o.w = acc[i][3] + b3;
    *(float4*)&XG[(size_t)(bb * TCH + tt) * G4 + col0] = o;
  }
}

// ---------------------------------------------------------------------------
// Persistent per-batch-row LSTM scan, R=2 gate rows per thread.
// 256 threads (4 waves): thread tid owns gate rows tid and tid+256, i.e.
// thread j<128 owns i[j],g[j]; thread j+128 owns f[j],o[j].
// Each ds_read_b128 of h feeds 8 FMAs (vs 4 in round 1); half the waves.
// h_s double-buffered; gates exchanged through fo_s; 2 barriers/step.
// ---------------------------------------------------------------------------
__global__ __launch_bounds__(256, 1)
void lstm_scan(const float* __restrict__ XG, const float* __restrict__ Whh,
               float* __restrict__ Hout, float* __restrict__ c_state, int t0)
{
  const int b   = blockIdx.x;
  const int tid = threadIdx.x;
  const int j   = tid & 127;
  const bool lower = tid < 128;
  __shared__ float h_s[2][HDIM];
  __shared__ float fo_s[2 * HDIM];

  float w0[HDIM], w1[HDIM];
  {
    const float4* wr0 = (const float4*)(Whh + (size_t)tid * HDIM);
    const float4* wr1 = (const float4*)(Whh + (size_t)(tid + 256) * HDIM);
    #pragma unroll
    for (int kk = 0; kk < 32; ++kk) {
      float4 v0 = wr0[kk];
      w0[4*kk+0] = v0.x; w0[4*kk+1] = v0.y; w0[4*kk+2] = v0.z; w0[4*kk+3] = v0.w;
      float4 v1 = wr1[kk];
      w1[4*kk+0] = v1.x; w1[4*kk+1] = v1.y; w1[4*kk+2] = v1.z; w1[4*kk+3] = v1.w;
    }
  }

  float c = 0.0f;
  if (lower) {
    if (t0 == 0) {
      h_s[0][j] = 0.0f;
    } else {
      h_s[0][j] = Hout[(size_t)(b * S_LEN + t0 - 1) * HDIM + j];
      c = c_state[b * HDIM + j];
    }
  }
  __syncthreads();

  const float* xgbase = XG + (size_t)b * TCH * G4;
  // 2-step-deep prefetch of xg (covers L2/LLC latency)
  float xg0_c = xgbase[tid];
  float xg1_c = xgbase[tid + 256];
  float xg0_n = xgbase[G4 + tid];
  float xg1_n = xgbase[G4 + tid + 256];

  for (int tt = 0; tt < TCH; ++tt) {
    const float xg0 = xg0_c, xg1 = xg1_c;
    xg0_c = xg0_n; xg1_c = xg1_n;
    const int tn = (tt + 2 < TCH) ? (tt + 2) : (TCH - 1);
    xg0_n = xgbase[(size_t)tn * G4 + tid];
    xg1_n = xgbase[(size_t)tn * G4 + tid + 256];

    const float4* h4 = (const float4*)h_s[tt & 1];
    float a0 = 0.f, a1 = 0.f, a2 = 0.f, a3 = 0.f;
    float e0 = 0.f, e1 = 0.f, e2 = 0.f, e3 = 0.f;
    #pragma unroll
    for (int kk = 0; kk < 32; ++kk) {
      float4 hv = h4[kk];               // uniform address -> LDS broadcast
      a0 = fmaf(w0[4*kk+0], hv.x, a0);
      a1 = fmaf(w0[4*kk+1], hv.y, a1);
      a2 = fmaf(w0[4*kk+2], hv.z, a2);
      a3 = fmaf(w0[4*kk+3], hv.w, a3);
      e0 = fmaf(w1[4*kk+0], hv.x, e0);
      e1 = fmaf(w1[4*kk+1], hv.y, e1);
      e2 = fmaf(w1[4*kk+2], hv.z, e2);
      e3 = fmaf(w1[4*kk+3], hv.w, e3);
    }
    const float d0 = xg0 + ((a0 + a1) + (a2 + a3));
    const float d1 = xg1 + ((e0 + e1) + (e2 + e3));
    if (!lower) { fo_s[j] = d0; fo_s[j + 128] = d1; }
    __syncthreads();
    if (lower) {
      float gi = fsig(d0);
      float gg = ftanh(d1);
      float gf = fsig(fo_s[j]);
      float go = fsig(fo_s[j + 128]);
      c = fmaf(gf, c, gi * gg);
      float h = go * ftanh(c);
      h_s[(tt & 1) ^ 1][j] = h;
      Hout[(size_t)(b * S_LEN + t0 + tt) * HDIM + j] = h;
    }
    __syncthreads();
  }
  if (lower) c_state[b * HDIM + j] = c;
}

// ---------------------------------------------------------------------------
// Attention pass 1 (unchanged)
// ---------------------------------------------------------------------------
__global__ __launch_bounds__(128)
void attn1(const float* __restrict__ Hs, const float* __restrict__ attn_w,
           const float* __restrict__ attn_b, const float* __restrict__ v_w,
           const float* __restrict__ v_b, float* __restrict__ logits)
{
  const int b  = blockIdx.x;
  const int tc = blockIdx.y;
  const int j  = threadIdx.x;
  float wreg[HDIM];
  {
    const float4* wr = (const float4*)(attn_w + (size_t)j * HDIM);
    #pragma unroll
    for (int kk = 0; kk < 32; ++kk) {
      float4 v = wr[kk];
      wreg[4*kk+0] = v.x; wreg[4*kk+1] = v.y; wreg[4*kk+2] = v.z; wreg[4*kk+3] = v.w;
    }
  }
  const float ab = attn_b[j];
  const float vw = v_w[j];
  const float vb = v_b[0];
  __shared__ float outs[16][HDIM];
  __shared__ float red[2];
  for (int t8 = 0; t8 < 8; ++t8) {
    const int tbase = tc * 128 + t8 * 16;
    for (int idx = j; idx < 16 * HDIM; idx += 128) {
      int rr = idx >> 7;
      int k  = idx & 127;
      outs[rr][k] = Hs[(size_t)(b * S_LEN + tbase + rr) * HDIM + k];
    }
    __syncthreads();
    for (int rr = 0; rr < 16; ++rr) {
      const float4* o4 = (const float4*)outs[rr];
      float a0 = 0.f, a1 = 0.f, a2 = 0.f, a3 = 0.f;
      #pragma unroll
      for (int kk = 0; kk < 32; ++kk) {
        float4 hv = o4[kk];
        a0 = fmaf(wreg[4*kk+0], hv.x, a0);
        a1 = fmaf(wreg[4*kk+1], hv.y, a1);
        a2 = fmaf(wreg[4*kk+2], hv.z, a2);
        a3 = fmaf(wreg[4*kk+3], hv.w, a3);
      }
      float s = ftanh(((a0 + a1) + (a2 + a3)) + ab) * vw;
      #pragma unroll
      for (int off = 1; off < 64; off <<= 1) s += __shfl_xor(s, off);
      if ((j & 63) == 0) red[j >> 6] = s;
      __syncthreads();
      if (j == 0) logits[b * S_LEN + tbase + rr] = red[0] + red[1] + vb;
      __syncthreads();
    }
  }
}

// ---------------------------------------------------------------------------
// Attention pass 2 (unchanged)
// ---------------------------------------------------------------------------
__global__ __launch_bounds__(128)
void attn2(const float* __restrict__ Hs, const float* __restrict__ logits,
           const float* __restrict__ fc_w, const float* __restrict__ fc_b,
           float* __restrict__ outp)
{
  const int b   = blockIdx.x;
  const int tid = threadIdx.x;
  __shared__ float pbuf[S_LEN];
  __shared__ float red[4];
  __shared__ float ctx_s[HDIM];
  float l0 = logits[b * S_LEN + tid];
  float l1 = logits[b * S_LEN + 128 + tid];
  float l2 = logits[b * S_LEN + 256 + tid];
  float l3 = logits[b * S_LEN + 384 + tid];
  float m = fmaxf(fmaxf(l0, l1), fmaxf(l2, l3));
  #pragma unroll
  for (int off = 1; off < 64; off <<= 1) m = fmaxf(m, __shfl_xor(m, off));
  if ((tid & 63) == 0) red[tid >> 6] = m;
  __syncthreads();
  m = fmaxf(red[0], red[1]);
  float p0 = __expf(l0 - m), p1 = __expf(l1 - m), p2 = __expf(l2 - m), p3 = __expf(l3 - m);
  pbuf[tid] = p0; pbuf[tid + 128] = p1; pbuf[tid + 256] = p2; pbuf[tid + 384] = p3;
  float sum = (p0 + p1) + (p2 + p3);
  #pragma unroll
  for (int off = 1; off < 64; off <<= 1) sum += __shfl_xor(sum, off);
  if ((tid & 63) == 0) red[2 + (tid >> 6)] = sum;
  __syncthreads();
  const float sinv = 1.0f / (red[2] + red[3]);
  float acc = 0.f;
  const float* hp = Hs + (size_t)b * S_LEN * HDIM + tid;
  #pragma unroll 4
  for (int t = 0; t < S_LEN; ++t) acc = fmaf(pbuf[t], hp[(size_t)t * HDIM], acc);
  ctx_s[tid] = acc * sinv;
  __syncthreads();
  if (tid < 7) {
    float a = fc_b[tid];
    const float* fw = fc_w + tid * HDIM;
    #pragma unroll 8
    for (int k = 0; k < HDIM; ++k) a = fmaf(ctx_s[k], fw[k], a);
    outp[b * 7 + tid] = a;
  }
}

// ---------------------------------------------------------------------------
extern "C" void kernel_launch(void* const* d_in, const int* in_sizes, int n_in,
                              void* d_out, int out_size, void* d_ws, size_t ws_size,
                              hipStream_t stream)
{
  const float* x      = (const float*)d_in[0];
  const float* w_ih0  = (const float*)d_in[1];
  const float* w_ih   = (const float*)d_in[2];
  const float* w_hh   = (const float*)d_in[3];
  const float* b_ih   = (const float*)d_in[4];
  const float* b_hh   = (const float*)d_in[5];
  const float* attn_w = (const float*)d_in[6];
  const float* attn_b = (const float*)d_in[7];
  const float* v_w    = (const float*)d_in[8];
  const float* v_b    = (const float*)d_in[9];
  const float* fc_w   = (const float*)d_in[10];
  const float* fc_b   = (const float*)d_in[11];
  float* outp = (float*)d_out;

  const size_t szXG = (size_t)BATCH * TCH * G4;
  const size_t szH  = (size_t)BATCH * S_LEN * HDIM;
  char* p = (char*)d_ws;
  float* XG = (float*)p;  p += szXG * 4;
  float* H0 = (float*)p;  p += szH * 4;
  float* H1 = (float*)p;  p += szH * 4;
  float* cst = (float*)p; p += (size_t)BATCH * HDIM * 4;
  float* lg  = (float*)p; p += (size_t)BATCH * S_LEN * 4;
  if ((size_t)(p - (char*)d_ws) > ws_size) return;

  for (int l = 0; l < NLAYER; ++l) {
    const float* Wih = (l == 0) ? w_ih0 : (w_ih + (size_t)(l - 1) * G4 * HDIM);
    const float* Ain = (l == 0) ? x : ((l & 1) ? H0 : H1);
    float* Ho = (l & 1) ? H1 : H0;
    const float* bi = b_ih + l * G4;
    const float* bh = b_hh + l * G4;
    const float* Wh = w_hh + (size_t)l * G4 * HDIM;
    for (int cch = 0; cch < NCH; ++cch) {
      int t0 = cch * TCH;
      if (l == 0)
        gemm_xg<27><<<dim3(BATCH * TCH / 64, G4 / 64), 256, 0, stream>>>(x, Wih, bi, bh, XG, t0);
      else
        gemm_xg<128><<<dim3(BATCH * TCH / 64, G4 / 64), 256, 0, stream>>>(Ain, Wih, bi, bh, XG, t0);
      lstm_scan<<<BATCH, 256, 0, stream>>>(XG, Wh, Ho, cst, t0);
    }
  }
  const float* Hlast = H1;
  attn1<<<dim3(BATCH, 4), 128, 0, stream>>>(Hlast, attn_w, attn_b, v_w, v_b, lg);
  attn2<<<BATCH, 128, 0, stream>>>(Hlast, lg, fc_w, fc_b, outp);
}

// Round 3
// 9096.825 us; speedup vs baseline: 1.3853x; 1.3853x over previous
//
#include <hip/hip_runtime.h>
#include <cstdint>
#include <cstddef>

#define S_LEN 512
#define TCH   128
#define NCH   4
#define HDIM  128
#define G4    512
#define BATCH 256
#define NLAYER 10

typedef float f32x4 __attribute__((ext_vector_type(4)));

__device__ __forceinline__ float fsig(float x) {
  return __builtin_amdgcn_rcpf(1.0f + __expf(-x));
}
__device__ __forceinline__ float ftanh(float x) {
  return fmaf(2.0f, __builtin_amdgcn_rcpf(1.0f + __expf(-2.0f * x)), -1.0f);
}

// ---------------------------------------------------------------------------
// Input-projection GEMM: XG[b][tt][g] = A[b, t0+tt, :] . W[g,:] + bih[g] + bhh[g]
// (unchanged: ~64 us/dispatch, ~43% of fp32 vector peak)
// ---------------------------------------------------------------------------
template<int K>
__global__ __launch_bounds__(256, 4)
void gemm_xg(const float* __restrict__ A, const float* __restrict__ W,
             const float* __restrict__ bih, const float* __restrict__ bhh,
             float* __restrict__ XG, int t0)
{
  constexpr int BK  = (K < 64) ? K : 64;
  constexpr int NKC = K / BK;
  __shared__ float As[BK][68];
  __shared__ float Bs[BK][68];
  const int tid = threadIdx.x;
  const int tx = tid & 15;
  const int ty = tid >> 4;
  const int rowBase = blockIdx.x * 64;
  const int colBase = blockIdx.y * 64;
  float acc[4][4] = {{0.f,0.f,0.f,0.f},{0.f,0.f,0.f,0.f},{0.f,0.f,0.f,0.f},{0.f,0.f,0.f,0.f}};

  for (int kc = 0; kc < NKC; ++kc) {
    const int kbase = kc * BK;
    for (int idx = tid; idx < 64 * BK; idx += 256) {
      int rr = idx / BK;
      int k  = idx - rr * BK;
      int r  = rowBase + rr;
      int bb = r >> 7;
      int tt = r & (TCH - 1);
      As[k][rr] = A[(size_t)(bb * S_LEN + t0 + tt) * K + kbase + k];
    }
    for (int idx = tid; idx < 64 * BK; idx += 256) {
      int cc = idx / BK;
      int k  = idx - cc * BK;
      Bs[k][cc] = W[(size_t)(colBase + cc) * K + kbase + k];
    }
    __syncthreads();
    #pragma unroll 8
    for (int k = 0; k < BK; ++k) {
      const float4 av = *(const float4*)&As[k][ty * 4];
      const float4 bv = *(const float4*)&Bs[k][tx * 4];
      float a_[4] = {av.x, av.y, av.z, av.w};
      float b_[4] = {bv.x, bv.y, bv.z, bv.w};
      #pragma unroll
      for (int i = 0; i < 4; ++i) {
        #pragma unroll
        for (int jj = 0; jj < 4; ++jj)
          acc[i][jj] = fmaf(a_[i], b_[jj], acc[i][jj]);
      }
    }
    __syncthreads();
  }

  const int col0 = colBase + tx * 4;
  const float4 bi4 = *(const float4*)&bih[col0];
  const float4 bh4 = *(const float4*)&bhh[col0];
  const float b0 = bi4.x + bh4.x, b1 = bi4.y + bh4.y, b2 = bi4.z + bh4.z, b3 = bi4.w + bh4.w;
  #pragma unroll
  for (int i = 0; i < 4; ++i) {
    int r  = rowBase + ty * 4 + i;
    int bb = r >> 7;
    int tt = r & (TCH - 1);
    float4 o;
    o.x = acc[i][0] + b0; o.y = acc[i][1] + b1; o.z = acc[i][2] + b2; o.w = acc[i][3] + b3;
    *(float4*)&XG[(size_t)(bb * TCH + tt) * G4 + col0] = o;
  }
}

// ---------------------------------------------------------------------------
// Persistent per-batch-row LSTM scan. 512 threads = 512 gate rows.
// W_hh row loaded ONCE into 32 float4 VGPR tuples; an opaque empty asm
// ("+v" pass-through) makes each value an asm-def so the register allocator
// CANNOT rematerialize the (loop-invariant, const-restrict) global loads
// inside the step loop — that remat was round 1/2's L2-BW bottleneck
// (256 KB/CU/step re-streamed, ~4500 cyc/step, VGPR_Count 120/144 < needed).
// h broadcast via uniform-address LDS reads; c in registers of threads 0..127.
// ---------------------------------------------------------------------------
__global__ __launch_bounds__(512, 2)
void lstm_scan(const float* __restrict__ XG, const float* __restrict__ Whh,
               float* __restrict__ Hout, float* __restrict__ c_state, int t0)
{
  const int b   = blockIdx.x;
  const int tid = threadIdx.x;
  __shared__ float h_s[2][HDIM];
  __shared__ float g_s[G4];

  f32x4 w4[32];
  {
    const f32x4* wr = (const f32x4*)(Whh + (size_t)tid * HDIM);
    #pragma unroll
    for (int kk = 0; kk < 32; ++kk) w4[kk] = wr[kk];
    // Block rematerialization: each w4[kk] becomes an asm-defined value the
    // RA must keep in registers (pressure fits: ~170 < 256 VGPR at 8 waves/CU).
    #pragma unroll
    for (int kk = 0; kk < 32; ++kk) asm("" : "+v"(w4[kk]));
  }

  float c = 0.0f;
  if (tid < HDIM) {
    if (t0 == 0) {
      h_s[0][tid] = 0.0f;
    } else {
      h_s[0][tid] = Hout[(size_t)(b * S_LEN + t0 - 1) * HDIM + tid];
      c = c_state[b * HDIM + tid];
    }
  }
  __syncthreads();

  const float* xgbase = XG + (size_t)b * TCH * G4;
  // 2-deep xg prefetch (covers L2/LLC latency under the dot product)
  float xg_c = xgbase[tid];
  float xg_n = xgbase[G4 + tid];

  for (int tt = 0; tt < TCH; ++tt) {
    const float xg = xg_c;
    xg_c = xg_n;
    const int tn = (tt + 2 < TCH) ? (tt + 2) : (TCH - 1);
    xg_n = xgbase[(size_t)tn * G4 + tid];

    const f32x4* h4 = (const f32x4*)h_s[tt & 1];
    float a0 = 0.f, a1 = 0.f, a2 = 0.f, a3 = 0.f;
    #pragma unroll
    for (int kk = 0; kk < 32; ++kk) {
      f32x4 hv = h4[kk];                 // uniform address -> LDS broadcast
      a0 = fmaf(w4[kk].x, hv.x, a0);
      a1 = fmaf(w4[kk].y, hv.y, a1);
      a2 = fmaf(w4[kk].z, hv.z, a2);
      a3 = fmaf(w4[kk].w, hv.w, a3);
    }
    g_s[tid] = xg + ((a0 + a1) + (a2 + a3));
    __syncthreads();
    if (tid < HDIM) {
      float gi = fsig(g_s[tid]);
      float gf = fsig(g_s[HDIM + tid]);
      float gg = ftanh(g_s[2*HDIM + tid]);
      float go = fsig(g_s[3*HDIM + tid]);
      c = fmaf(gf, c, gi * gg);
      float h = go * ftanh(c);
      h_s[(tt & 1) ^ 1][tid] = h;
      Hout[(size_t)(b * S_LEN + t0 + tt) * HDIM + tid] = h;
    }
    __syncthreads();
  }
  if (tid < HDIM) c_state[b * HDIM + tid] = c;
}

// ---------------------------------------------------------------------------
// Attention pass 1 (unchanged)
// ---------------------------------------------------------------------------
__global__ __launch_bounds__(128)
void attn1(const float* __restrict__ Hs, const float* __restrict__ attn_w,
           const float* __restrict__ attn_b, const float* __restrict__ v_w,
           const float* __restrict__ v_b, float* __restrict__ logits)
{
  const int b  = blockIdx.x;
  const int tc = blockIdx.y;
  const int j  = threadIdx.x;
  float wreg[HDIM];
  {
    const float4* wr = (const float4*)(attn_w + (size_t)j * HDIM);
    #pragma unroll
    for (int kk = 0; kk < 32; ++kk) {
      float4 v = wr[kk];
      wreg[4*kk+0] = v.x; wreg[4*kk+1] = v.y; wreg[4*kk+2] = v.z; wreg[4*kk+3] = v.w;
    }
  }
  const float ab = attn_b[j];
  const float vw = v_w[j];
  const float vb = v_b[0];
  __shared__ float outs[16][HDIM];
  __shared__ float red[2];
  for (int t8 = 0; t8 < 8; ++t8) {
    const int tbase = tc * 128 + t8 * 16;
    for (int idx = j; idx < 16 * HDIM; idx += 128) {
      int rr = idx >> 7;
      int k  = idx & 127;
      outs[rr][k] = Hs[(size_t)(b * S_LEN + tbase + rr) * HDIM + k];
    }
    __syncthreads();
    for (int rr = 0; rr < 16; ++rr) {
      const float4* o4 = (const float4*)outs[rr];
      float a0 = 0.f, a1 = 0.f, a2 = 0.f, a3 = 0.f;
      #pragma unroll
      for (int kk = 0; kk < 32; ++kk) {
        float4 hv = o4[kk];
        a0 = fmaf(wreg[4*kk+0], hv.x, a0);
        a1 = fmaf(wreg[4*kk+1], hv.y, a1);
        a2 = fmaf(wreg[4*kk+2], hv.z, a2);
        a3 = fmaf(wreg[4*kk+3], hv.w, a3);
      }
      float s = ftanh(((a0 + a1) + (a2 + a3)) + ab) * vw;
      #pragma unroll
      for (int off = 1; off < 64; off <<= 1) s += __shfl_xor(s, off);
      if ((j & 63) == 0) red[j >> 6] = s;
      __syncthreads();
      if (j == 0) logits[b * S_LEN + tbase + rr] = red[0] + red[1] + vb;
      __syncthreads();
    }
  }
}

// ---------------------------------------------------------------------------
// Attention pass 2 (unchanged)
// ---------------------------------------------------------------------------
__global__ __launch_bounds__(128)
void attn2(const float* __restrict__ Hs, const float* __restrict__ logits,
           const float* __restrict__ fc_w, const float* __restrict__ fc_b,
           float* __restrict__ outp)
{
  const int b   = blockIdx.x;
  const int tid = threadIdx.x;
  __shared__ float pbuf[S_LEN];
  __shared__ float red[4];
  __shared__ float ctx_s[HDIM];
  float l0 = logits[b * S_LEN + tid];
  float l1 = logits[b * S_LEN + 128 + tid];
  float l2 = logits[b * S_LEN + 256 + tid];
  float l3 = logits[b * S_LEN + 384 + tid];
  float m = fmaxf(fmaxf(l0, l1), fmaxf(l2, l3));
  #pragma unroll
  for (int off = 1; off < 64; off <<= 1) m = fmaxf(m, __shfl_xor(m, off));
  if ((tid & 63) == 0) red[tid >> 6] = m;
  __syncthreads();
  m = fmaxf(red[0], red[1]);
  float p0 = __expf(l0 - m), p1 = __expf(l1 - m), p2 = __expf(l2 - m), p3 = __expf(l3 - m);
  pbuf[tid] = p0; pbuf[tid + 128] = p1; pbuf[tid + 256] = p2; pbuf[tid + 384] = p3;
  float sum = (p0 + p1) + (p2 + p3);
  #pragma unroll
  for (int off = 1; off < 64; off <<= 1) sum += __shfl_xor(sum, off);
  if ((tid & 63) == 0) red[2 + (tid >> 6)] = sum;
  __syncthreads();
  const float sinv = 1.0f / (red[2] + red[3]);
  float acc = 0.f;
  const float* hp = Hs + (size_t)b * S_LEN * HDIM + tid;
  #pragma unroll 4
  for (int t = 0; t < S_LEN; ++t) acc = fmaf(pbuf[t], hp[(size_t)t * HDIM], acc);
  ctx_s[tid] = acc * sinv;
  __syncthreads();
  if (tid < 7) {
    float a = fc_b[tid];
    const float* fw = fc_w + tid * HDIM;
    #pragma unroll 8
    for (int k = 0; k < HDIM; ++k) a = fmaf(ctx_s[k], fw[k], a);
    outp[b * 7 + tid] = a;
  }
}

// ---------------------------------------------------------------------------
extern "C" void kernel_launch(void* const* d_in, const int* in_sizes, int n_in,
                              void* d_out, int out_size, void* d_ws, size_t ws_size,
                              hipStream_t stream)
{
  const float* x      = (const float*)d_in[0];
  const float* w_ih0  = (const float*)d_in[1];
  const float* w_ih   = (const float*)d_in[2];
  const float* w_hh   = (const float*)d_in[3];
  const float* b_ih   = (const float*)d_in[4];
  const float* b_hh   = (const float*)d_in[5];
  const float* attn_w = (const float*)d_in[6];
  const float* attn_b = (const float*)d_in[7];
  const float* v_w    = (const float*)d_in[8];
  const float* v_b    = (const float*)d_in[9];
  const float* fc_w   = (const float*)d_in[10];
  const float* fc_b   = (const float*)d_in[11];
  float* outp = (float*)d_out;

  const size_t szXG = (size_t)BATCH * TCH * G4;
  const size_t szH  = (size_t)BATCH * S_LEN * HDIM;
  char* p = (char*)d_ws;
  float* XG = (float*)p;  p += szXG * 4;
  float* H0 = (float*)p;  p += szH * 4;
  float* H1 = (float*)p;  p += szH * 4;
  float* cst = (float*)p; p += (size_t)BATCH * HDIM * 4;
  float* lg  = (float*)p; p += (size_t)BATCH * S_LEN * 4;
  if ((size_t)(p - (char*)d_ws) > ws_size) return;

  for (int l = 0; l < NLAYER; ++l) {
    const float* Wih = (l == 0) ? w_ih0 : (w_ih + (size_t)(l - 1) * G4 * HDIM);
    const float* Ain = (l == 0) ? x : ((l & 1) ? H0 : H1);
    float* Ho = (l & 1) ? H1 : H0;
    const float* bi = b_ih + l * G4;
    const float* bh = b_hh + l * G4;
    const float* Wh = w_hh + (size_t)l * G4 * HDIM;
    for (int cch = 0; cch < NCH; ++cch) {
      int t0 = cch * TCH;
      if (l == 0)
        gemm_xg<27><<<dim3(BATCH * TCH / 64, G4 / 64), 256, 0, stream>>>(x, Wih, bi, bh, XG, t0);
      else
        gemm_xg<128><<<dim3(BATCH * TCH / 64, G4 / 64), 256, 0, stream>>>(Ain, Wih, bi, bh, XG, t0);
      lstm_scan<<<BATCH, 512, 0, stream>>>(XG, Wh, Ho, cst, t0);
    }
  }
  const float* Hlast = H1;
  attn1<<<dim3(BATCH, 4), 128, 0, stream>>>(Hlast, attn_w, attn_b, v_w, v_b, lg);
  attn2<<<BATCH, 128, 0, stream>>>(Hlast, lg, fc_w, fc_b, outp);
}

// Round 4
// 7944.117 us; speedup vs baseline: 1.5863x; 1.1451x over previous
//
#include <hip/hip_runtime.h>
#include <cstdint>
#include <cstddef>

#define S_LEN 512
#define TCH   128
#define NCH   4
#define HDIM  128
#define G4    512
#define BATCH 256
#define NLAYER 10

typedef float f32x4 __attribute__((ext_vector_type(4)));

__device__ __forceinline__ float fsig(float x) {
  return __builtin_amdgcn_rcpf(1.0f + __expf(-x));
}
__device__ __forceinline__ float ftanh(float x) {
  return fmaf(2.0f, __builtin_amdgcn_rcpf(1.0f + __expf(-2.0f * x)), -1.0f);
}

// ---------------------------------------------------------------------------
// Input-projection GEMM (unchanged: ~64 us/dispatch, ~43% of fp32 vector peak)
// ---------------------------------------------------------------------------
template<int K>
__global__ __launch_bounds__(256, 4)
void gemm_xg(const float* __restrict__ A, const float* __restrict__ W,
             const float* __restrict__ bih, const float* __restrict__ bhh,
             float* __restrict__ XG, int t0)
{
  constexpr int BK  = (K < 64) ? K : 64;
  constexpr int NKC = K / BK;
  __shared__ float As[BK][68];
  __shared__ float Bs[BK][68];
  const int tid = threadIdx.x;
  const int tx = tid & 15;
  const int ty = tid >> 4;
  const int rowBase = blockIdx.x * 64;
  const int colBase = blockIdx.y * 64;
  float acc[4][4] = {{0.f,0.f,0.f,0.f},{0.f,0.f,0.f,0.f},{0.f,0.f,0.f,0.f},{0.f,0.f,0.f,0.f}};

  for (int kc = 0; kc < NKC; ++kc) {
    const int kbase = kc * BK;
    for (int idx = tid; idx < 64 * BK; idx += 256) {
      int rr = idx / BK;
      int k  = idx - rr * BK;
      int r  = rowBase + rr;
      int bb = r >> 7;
      int tt = r & (TCH - 1);
      As[k][rr] = A[(size_t)(bb * S_LEN + t0 + tt) * K + kbase + k];
    }
    for (int idx = tid; idx < 64 * BK; idx += 256) {
      int cc = idx / BK;
      int k  = idx - cc * BK;
      Bs[k][cc] = W[(size_t)(colBase + cc) * K + kbase + k];
    }
    __syncthreads();
    #pragma unroll 8
    for (int k = 0; k < BK; ++k) {
      const float4 av = *(const float4*)&As[k][ty * 4];
      const float4 bv = *(const float4*)&Bs[k][tx * 4];
      float a_[4] = {av.x, av.y, av.z, av.w};
      float b_[4] = {bv.x, bv.y, bv.z, bv.w};
      #pragma unroll
      for (int i = 0; i < 4; ++i) {
        #pragma unroll
        for (int jj = 0; jj < 4; ++jj)
          acc[i][jj] = fmaf(a_[i], b_[jj], acc[i][jj]);
      }
    }
    __syncthreads();
  }

  const int col0 = colBase + tx * 4;
  const float4 bi4 = *(const float4*)&bih[col0];
  const float4 bh4 = *(const float4*)&bhh[col0];
  const float b0 = bi4.x + bh4.x, b1 = bi4.y + bh4.y, b2 = bi4.z + bh4.z, b3 = bi4.w + bh4.w;
  #pragma unroll
  for (int i = 0; i < 4; ++i) {
    int r  = rowBase + ty * 4 + i;
    int bb = r >> 7;
    int tt = r & (TCH - 1);
    float4 o;
    o.x = acc[i][0] + b0; o.y = acc[i][1] + b1; o.z = acc[i][2] + b2; o.w = acc[i][3] + b3;
    *(float4*)&XG[(size_t)(bb * TCH + tt) * G4 + col0] = o;
  }
}

// ---------------------------------------------------------------------------
// Persistent per-batch-row LSTM scan, 1024 threads (16 waves).
// Thread tid = (row = tid&511, khalf = tid>>9): owns HALF a W_hh gate row --
// 64 floats = 16 f32x4 = 64 VGPRs. This is small enough that the register
// allocator genuinely keeps the weights resident (rounds 1-3 showed it
// spills/re-streams at 128 floats/thread: FETCH_SIZE 33.8MB = Whh x 128
// steps, ~2960 cyc/step L2-bound).
// Per step: half-dot vs h (wave-uniform LDS broadcast) -> partial into
// pp[row].{x,y} (kh=0 folds xg in) -> barrier -> threads 0..127 read 4 gate
// rows' float2, activations, c/h update, write h_s+Hout -> barrier.
// ---------------------------------------------------------------------------
__global__ __launch_bounds__(1024, 4)
void lstm_scan(const float* __restrict__ XG, const float* __restrict__ Whh,
               float* __restrict__ Hout, float* __restrict__ c_state, int t0)
{
  const int b   = blockIdx.x;
  const int tid = threadIdx.x;
  const int row = tid & 511;
  const int kh  = tid >> 9;          // 0: k in [0,64), 1: k in [64,128)
  __shared__ float h_s[2][HDIM];
  __shared__ float2 pp[G4];          // per-row partials {kh0 + xg, kh1}

  f32x4 w4[16];
  {
    const f32x4* wr = (const f32x4*)(Whh + (size_t)row * HDIM + kh * 64);
    #pragma unroll
    for (int kk = 0; kk < 16; ++kk) w4[kk] = wr[kk];
    #pragma unroll
    for (int kk = 0; kk < 16; ++kk) asm("" : "+v"(w4[kk]));  // opaque: no remat
  }

  float c = 0.0f;
  if (tid < HDIM) {
    if (t0 == 0) {
      h_s[0][tid] = 0.0f;
    } else {
      h_s[0][tid] = Hout[(size_t)(b * S_LEN + t0 - 1) * HDIM + tid];
      c = c_state[b * HDIM + tid];
    }
  }
  __syncthreads();

  const float* xgbase = XG + (size_t)b * TCH * G4;
  // 2-deep xg prefetch, kh==0 waves only (wave-uniform branch)
  float xg_c = 0.f, xg_n = 0.f;
  if (kh == 0) {
    xg_c = xgbase[row];
    xg_n = xgbase[G4 + row];
  }

  for (int tt = 0; tt < TCH; ++tt) {
    const float xg = xg_c;
    xg_c = xg_n;
    if (kh == 0) {
      const int tn = (tt + 2 < TCH) ? (tt + 2) : (TCH - 1);
      xg_n = xgbase[(size_t)tn * G4 + row];
    }

    const f32x4* h4 = (const f32x4*)&h_s[tt & 1][kh * 64];
    float a0 = 0.f, a1 = 0.f, a2 = 0.f, a3 = 0.f;
    #pragma unroll
    for (int kk = 0; kk < 16; ++kk) {
      f32x4 hv = h4[kk];               // wave-uniform address -> LDS broadcast
      a0 = fmaf(w4[kk].x, hv.x, a0);
      a1 = fmaf(w4[kk].y, hv.y, a1);
      a2 = fmaf(w4[kk].z, hv.z, a2);
      a3 = fmaf(w4[kk].w, hv.w, a3);
    }
    const float p = (a0 + a1) + (a2 + a3);
    if (kh == 0) pp[row].x = p + xg;
    else         pp[row].y = p;
    __syncthreads();
    if (tid < HDIM) {
      float2 pi = pp[tid];
      float2 pf = pp[HDIM + tid];
      float2 pg = pp[2 * HDIM + tid];
      float2 po = pp[3 * HDIM + tid];
      float gi = fsig(pi.x + pi.y);
      float gf = fsig(pf.x + pf.y);
      float gg = ftanh(pg.x + pg.y);
      float go = fsig(po.x + po.y);
      c = fmaf(gf, c, gi * gg);
      float h = go * ftanh(c);
      h_s[(tt & 1) ^ 1][tid] = h;
      Hout[(size_t)(b * S_LEN + t0 + tt) * HDIM + tid] = h;
    }
    __syncthreads();
  }
  if (tid < HDIM) c_state[b * HDIM + tid] = c;
}

// ---------------------------------------------------------------------------
// Attention pass 1 (unchanged)
// ---------------------------------------------------------------------------
__global__ __launch_bounds__(128)
void attn1(const float* __restrict__ Hs, const float* __restrict__ attn_w,
           const float* __restrict__ attn_b, const float* __restrict__ v_w,
           const float* __restrict__ v_b, float* __restrict__ logits)
{
  const int b  = blockIdx.x;
  const int tc = blockIdx.y;
  const int j  = threadIdx.x;
  float wreg[HDIM];
  {
    const float4* wr = (const float4*)(attn_w + (size_t)j * HDIM);
    #pragma unroll
    for (int kk = 0; kk < 32; ++kk) {
      float4 v = wr[kk];
      wreg[4*kk+0] = v.x; wreg[4*kk+1] = v.y; wreg[4*kk+2] = v.z; wreg[4*kk+3] = v.w;
    }
  }
  const float ab = attn_b[j];
  const float vw = v_w[j];
  const float vb = v_b[0];
  __shared__ float outs[16][HDIM];
  __shared__ float red[2];
  for (int t8 = 0; t8 < 8; ++t8) {
    const int tbase = tc * 128 + t8 * 16;
    for (int idx = j; idx < 16 * HDIM; idx += 128) {
      int rr = idx >> 7;
      int k  = idx & 127;
      outs[rr][k] = Hs[(size_t)(b * S_LEN + tbase + rr) * HDIM + k];
    }
    __syncthreads();
    for (int rr = 0; rr < 16; ++rr) {
      const float4* o4 = (const float4*)outs[rr];
      float a0 = 0.f, a1 = 0.f, a2 = 0.f, a3 = 0.f;
      #pragma unroll
      for (int kk = 0; kk < 32; ++kk) {
        float4 hv = o4[kk];
        a0 = fmaf(wreg[4*kk+0], hv.x, a0);
        a1 = fmaf(wreg[4*kk+1], hv.y, a1);
        a2 = fmaf(wreg[4*kk+2], hv.z, a2);
        a3 = fmaf(wreg[4*kk+3], hv.w, a3);
      }
      float s = ftanh(((a0 + a1) + (a2 + a3)) + ab) * vw;
      #pragma unroll
      for (int off = 1; off < 64; off <<= 1) s += __shfl_xor(s, off);
      if ((j & 63) == 0) red[j >> 6] = s;
      __syncthreads();
      if (j == 0) logits[b * S_LEN + tbase + rr] = red[0] + red[1] + vb;
      __syncthreads();
    }
  }
}

// ---------------------------------------------------------------------------
// Attention pass 2 (unchanged)
// ---------------------------------------------------------------------------
__global__ __launch_bounds__(128)
void attn2(const float* __restrict__ Hs, const float* __restrict__ logits,
           const float* __restrict__ fc_w, const float* __restrict__ fc_b,
           float* __restrict__ outp)
{
  const int b   = blockIdx.x;
  const int tid = threadIdx.x;
  __shared__ float pbuf[S_LEN];
  __shared__ float red[4];
  __shared__ float ctx_s[HDIM];
  float l0 = logits[b * S_LEN + tid];
  float l1 = logits[b * S_LEN + 128 + tid];
  float l2 = logits[b * S_LEN + 256 + tid];
  float l3 = logits[b * S_LEN + 384 + tid];
  float m = fmaxf(fmaxf(l0, l1), fmaxf(l2, l3));
  #pragma unroll
  for (int off = 1; off < 64; off <<= 1) m = fmaxf(m, __shfl_xor(m, off));
  if ((tid & 63) == 0) red[tid >> 6] = m;
  __syncthreads();
  m = fmaxf(red[0], red[1]);
  float p0 = __expf(l0 - m), p1 = __expf(l1 - m), p2 = __expf(l2 - m), p3 = __expf(l3 - m);
  pbuf[tid] = p0; pbuf[tid + 128] = p1; pbuf[tid + 256] = p2; pbuf[tid + 384] = p3;
  float sum = (p0 + p1) + (p2 + p3);
  #pragma unroll
  for (int off = 1; off < 64; off <<= 1) sum += __shfl_xor(sum, off);
  if ((tid & 63) == 0) red[2 + (tid >> 6)] = sum;
  __syncthreads();
  const float sinv = 1.0f / (red[2] + red[3]);
  float acc = 0.f;
  const float* hp = Hs + (size_t)b * S_LEN * HDIM + tid;
  #pragma unroll 4
  for (int t = 0; t < S_LEN; ++t) acc = fmaf(pbuf[t], hp[(size_t)t * HDIM], acc);
  ctx_s[tid] = acc * sinv;
  __syncthreads();
  if (tid < 7) {
    float a = fc_b[tid];
    const float* fw = fc_w + tid * HDIM;
    #pragma unroll 8
    for (int k = 0; k < HDIM; ++k) a = fmaf(ctx_s[k], fw[k], a);
    outp[b * 7 + tid] = a;
  }
}

// ---------------------------------------------------------------------------
extern "C" void kernel_launch(void* const* d_in, const int* in_sizes, int n_in,
                              void* d_out, int out_size, void* d_ws, size_t ws_size,
                              hipStream_t stream)
{
  const float* x      = (const float*)d_in[0];
  const float* w_ih0  = (const float*)d_in[1];
  const float* w_ih   = (const float*)d_in[2];
  const float* w_hh   = (const float*)d_in[3];
  const float* b_ih   = (const float*)d_in[4];
  const float* b_hh   = (const float*)d_in[5];
  const float* attn_w = (const float*)d_in[6];
  const float* attn_b = (const float*)d_in[7];
  const float* v_w    = (const float*)d_in[8];
  const float* v_b    = (const float*)d_in[9];
  const float* fc_w   = (const float*)d_in[10];
  const float* fc_b   = (const float*)d_in[11];
  float* outp = (float*)d_out;

  const size_t szXG = (size_t)BATCH * TCH * G4;
  const size_t szH  = (size_t)BATCH * S_LEN * HDIM;
  char* p = (char*)d_ws;
  float* XG = (float*)p;  p += szXG * 4;
  float* H0 = (float*)p;  p += szH * 4;
  float* H1 = (float*)p;  p += szH * 4;
  float* cst = (float*)p; p += (size_t)BATCH * HDIM * 4;
  float* lg  = (float*)p; p += (size_t)BATCH * S_LEN * 4;
  if ((size_t)(p - (char*)d_ws) > ws_size) return;

  for (int l = 0; l < NLAYER; ++l) {
    const float* Wih = (l == 0) ? w_ih0 : (w_ih + (size_t)(l - 1) * G4 * HDIM);
    const float* Ain = (l == 0) ? x : ((l & 1) ? H0 : H1);
    float* Ho = (l & 1) ? H1 : H0;
    const float* bi = b_ih + l * G4;
    const float* bh = b_hh + l * G4;
    const float* Wh = w_hh + (size_t)l * G4 * HDIM;
    for (int cch = 0; cch < NCH; ++cch) {
      int t0 = cch * TCH;
      if (l == 0)
        gemm_xg<27><<<dim3(BATCH * TCH / 64, G4 / 64), 256, 0, stream>>>(x, Wih, bi, bh, XG, t0);
      else
        gemm_xg<128><<<dim3(BATCH * TCH / 64, G4 / 64), 256, 0, stream>>>(Ain, Wih, bi, bh, XG, t0);
      lstm_scan<<<BATCH, 1024, 0, stream>>>(XG, Wh, Ho, cst, t0);
    }
  }
  const float* Hlast = H1;
  attn1<<<dim3(BATCH, 4), 128, 0, stream>>>(Hlast, attn_w, attn_b, v_w, v_b, lg);
  attn2<<<BATCH, 128, 0, stream>>>(Hlast, lg, fc_w, fc_b, outp);
}

// Round 5
// 7334.896 us; speedup vs baseline: 1.7180x; 1.0831x over previous
//
#include <hip/hip_runtime.h>
#include <cstdint>
#include <cstddef>

#define S_LEN 512
#define TCH   128
#define NCH   4
#define HDIM  128
#define G4    512
#define BATCH 256
#define NLAYER 10

typedef float f32x4 __attribute__((ext_vector_type(4)));
typedef short short8 __attribute__((ext_vector_type(8)));

__device__ __forceinline__ float fsig(float x) {
  return __builtin_amdgcn_rcpf(1.0f + __expf(-x));
}
__device__ __forceinline__ float ftanh(float x) {
  return fmaf(2.0f, __builtin_amdgcn_rcpf(1.0f + __expf(-2.0f * x)), -1.0f);
}
__device__ __forceinline__ unsigned short bf16_rne(float x) {
  unsigned int u = __float_as_uint(x);
  unsigned int r = (u + 0x7fffu + ((u >> 16) & 1u)) >> 16;
  return (unsigned short)r;
}
__device__ __forceinline__ float bf16_to_f(unsigned short h) {
  return __uint_as_float(((unsigned int)h) << 16);
}

// ---------------------------------------------------------------------------
// Split fp32 weights into (hi, lo) bf16 pair: x ~= hi + lo, |lo| <= 2^-8 |x|.
// Run once per kernel_launch over all 9 layers' w_ih.
// ---------------------------------------------------------------------------
__global__ void split_w(const float* __restrict__ W, unsigned short* __restrict__ hi,
                        unsigned short* __restrict__ lo, int n)
{
  int i = blockIdx.x * 256 + threadIdx.x;
  if (i < n) {
    float x = W[i];
    unsigned short h = bf16_rne(x);
    hi[i] = h;
    lo[i] = bf16_rne(x - bf16_to_f(h));
  }
}

// ---------------------------------------------------------------------------
// Layer-0 input GEMM (K=27), fp32 VALU — tiny (4 dispatches, ~15us each).
// ---------------------------------------------------------------------------
template<int K>
__global__ __launch_bounds__(256, 4)
void gemm_xg(const float* __restrict__ A, const float* __restrict__ W,
             const float* __restrict__ bih, const float* __restrict__ bhh,
             float* __restrict__ XG, int t0)
{
  constexpr int BK  = (K < 64) ? K : 64;
  constexpr int NKC = K / BK;
  __shared__ float As[BK][68];
  __shared__ float Bs[BK][68];
  const int tid = threadIdx.x;
  const int tx = tid & 15;
  const int ty = tid >> 4;
  const int rowBase = blockIdx.x * 64;
  const int colBase = blockIdx.y * 64;
  float acc[4][4] = {{0.f,0.f,0.f,0.f},{0.f,0.f,0.f,0.f},{0.f,0.f,0.f,0.f},{0.f,0.f,0.f,0.f}};

  for (int kc = 0; kc < NKC; ++kc) {
    const int kbase = kc * BK;
    for (int idx = tid; idx < 64 * BK; idx += 256) {
      int rr = idx / BK;
      int k  = idx - rr * BK;
      int r  = rowBase + rr;
      int bb = r >> 7;
      int tt = r & (TCH - 1);
      As[k][rr] = A[(size_t)(bb * S_LEN + t0 + tt) * K + kbase + k];
    }
    for (int idx = tid; idx < 64 * BK; idx += 256) {
      int cc = idx / BK;
      int k  = idx - cc * BK;
      Bs[k][cc] = W[(size_t)(colBase + cc) * K + kbase + k];
    }
    __syncthreads();
    #pragma unroll 8
    for (int k = 0; k < BK; ++k) {
      const float4 av = *(const float4*)&As[k][ty * 4];
      const float4 bv = *(const float4*)&Bs[k][tx * 4];
      float a_[4] = {av.x, av.y, av.z, av.w};
      float b_[4] = {bv.x, bv.y, bv.z, bv.w};
      #pragma unroll
      for (int i = 0; i < 4; ++i) {
        #pragma unroll
        for (int jj = 0; jj < 4; ++jj)
          acc[i][jj] = fmaf(a_[i], b_[jj], acc[i][jj]);
      }
    }
    __syncthreads();
  }

  const int col0 = colBase + tx * 4;
  const float4 bi4 = *(const float4*)&bih[col0];
  const float4 bh4 = *(const float4*)&bhh[col0];
  const float b0 = bi4.x + bh4.x, b1 = bi4.y + bh4.y, b2 = bi4.z + bh4.z, b3 = bi4.w + bh4.w;
  #pragma unroll
  for (int i = 0; i < 4; ++i) {
    int r  = rowBase + ty * 4 + i;
    int bb = r >> 7;
    int tt = r & (TCH - 1);
    float4 o;
    o.x = acc[i][0] + b0; o.y = acc[i][1] + b1; o.z = acc[i][2] + b2; o.w = acc[i][3] + b3;
    *(float4*)&XG[(size_t)(bb * TCH + tt) * G4 + col0] = o;
  }
}

// ---------------------------------------------------------------------------
// Split-bf16 MFMA input GEMM for layers 1..9 (K=HDIM=128).
// XG[r][n] = sum_k A[r][k] * W[n][k] + bias[n], with A,W fp32 split into
// bf16 hi/lo and 3-term accumulation (hi*hi + hi*lo + lo*hi) in fp32 MFMA.
// Tile 64 rows x 64 gates; 4 waves, each wave a 16-row band x 64 cols.
// A staged+converted in LDS; W read pre-split from global (L2-hot).
// Fragment layouts (guide 3, m89/m91-verified family):
//   A/B frag: lane holds 8 contiguous k at row/col = lane&15, k-group (lane>>4)*8
//   C/D: col = lane&15, row = (lane>>4)*4 + reg
// ---------------------------------------------------------------------------
__global__ __launch_bounds__(256, 2)
void gemm_xg_mfma(const float* __restrict__ A,
                  const unsigned short* __restrict__ Whi,
                  const unsigned short* __restrict__ Wlo,
                  const float* __restrict__ bih, const float* __restrict__ bhh,
                  float* __restrict__ XG, int t0)
{
  __shared__ unsigned short Ahi[64][136];   // pad 8 ushorts: 272B rows, 2-way-max banks
  __shared__ unsigned short Alo[64][136];
  const int tid = threadIdx.x;
  const int rowBase = blockIdx.x * 64;      // in [0, 32768)
  const int colBase = blockIdx.y * 64;      // in [0, 512)

  // Stage A: 64 rows x 128 k fp32 -> bf16 hi/lo in LDS. 4 iters x 256 thr,
  // each iter converts 8 consecutive k of one row.
  #pragma unroll
  for (int it = 0; it < 4; ++it) {
    int idx = tid + it * 256;
    int rr  = idx >> 4;
    int kg  = (idx & 15) * 8;
    int r   = rowBase + rr;
    int bb  = r >> 7;
    int tt  = r & (TCH - 1);
    const float* ap = &A[(size_t)(bb * S_LEN + t0 + tt) * HDIM + kg];
    float4 v0 = *(const float4*)ap;
    float4 v1 = *(const float4*)(ap + 4);
    float xs[8] = {v0.x, v0.y, v0.z, v0.w, v1.x, v1.y, v1.z, v1.w};
    unsigned short h[8], l[8];
    #pragma unroll
    for (int j = 0; j < 8; ++j) {
      h[j] = bf16_rne(xs[j]);
      l[j] = bf16_rne(xs[j] - bf16_to_f(h[j]));
    }
    *(short8*)&Ahi[rr][kg] = *(short8*)h;
    *(short8*)&Alo[rr][kg] = *(short8*)l;
  }
  __syncthreads();

  const int w  = tid >> 6;          // wave 0..3 -> row band w*16
  const int ln = tid & 63;
  const int fr = ln & 15;           // frag row/col index
  const int kgrp = (ln >> 4) * 8;   // frag k-offset within 32-wide K-step

  f32x4 acc[4] = {};
  #pragma unroll
  for (int ks = 0; ks < 4; ++ks) {
    const int k0 = ks * 32 + kgrp;
    short8 ah = *(const short8*)&Ahi[(w << 4) + fr][k0];
    short8 al = *(const short8*)&Alo[(w << 4) + fr][k0];
    #pragma unroll
    for (int nt = 0; nt < 4; ++nt) {
      const int col = colBase + nt * 16 + fr;
      short8 bh = *(const short8*)&Whi[(size_t)col * HDIM + k0];
      short8 bl = *(const short8*)&Wlo[(size_t)col * HDIM + k0];
      acc[nt] = __builtin_amdgcn_mfma_f32_16x16x32_bf16(ah, bh, acc[nt], 0, 0, 0);
      acc[nt] = __builtin_amdgcn_mfma_f32_16x16x32_bf16(ah, bl, acc[nt], 0, 0, 0);
      acc[nt] = __builtin_amdgcn_mfma_f32_16x16x32_bf16(al, bh, acc[nt], 0, 0, 0);
    }
  }

  // Epilogue: C/D mapping col = lane&15, row = (lane>>4)*4 + reg.
  #pragma unroll
  for (int nt = 0; nt < 4; ++nt) {
    const int col = colBase + nt * 16 + fr;
    const float bsum = bih[col] + bhh[col];
    #pragma unroll
    for (int j = 0; j < 4; ++j) {
      int r  = rowBase + (w << 4) + ((ln >> 4) << 2) + j;
      int bb = r >> 7;
      int tt = r & (TCH - 1);
      XG[(size_t)(bb * TCH + tt) * G4 + col] = acc[nt][j] + bsum;
    }
  }
}

// ---------------------------------------------------------------------------
// Persistent per-batch-row LSTM scan, 1024 threads (unchanged from round 4:
// ~129us/dispatch; LDS-broadcast data-path-bound at ~256 ds_read_b128/step).
// ---------------------------------------------------------------------------
__global__ __launch_bounds__(1024, 4)
void lstm_scan(const float* __restrict__ XG, const float* __restrict__ Whh,
               float* __restrict__ Hout, float* __restrict__ c_state, int t0)
{
  const int b   = blockIdx.x;
  const int tid = threadIdx.x;
  const int row = tid & 511;
  const int kh  = tid >> 9;
  __shared__ float h_s[2][HDIM];
  __shared__ float2 pp[G4];

  f32x4 w4[16];
  {
    const f32x4* wr = (const f32x4*)(Whh + (size_t)row * HDIM + kh * 64);
    #pragma unroll
    for (int kk = 0; kk < 16; ++kk) w4[kk] = wr[kk];
    #pragma unroll
    for (int kk = 0; kk < 16; ++kk) asm("" : "+v"(w4[kk]));
  }

  float c = 0.0f;
  if (tid < HDIM) {
    if (t0 == 0) {
      h_s[0][tid] = 0.0f;
    } else {
      h_s[0][tid] = Hout[(size_t)(b * S_LEN + t0 - 1) * HDIM + tid];
      c = c_state[b * HDIM + tid];
    }
  }
  __syncthreads();

  const float* xgbase = XG + (size_t)b * TCH * G4;
  float xg_c = 0.f, xg_n = 0.f;
  if (kh == 0) {
    xg_c = xgbase[row];
    xg_n = xgbase[G4 + row];
  }

  for (int tt = 0; tt < TCH; ++tt) {
    const float xg = xg_c;
    xg_c = xg_n;
    if (kh == 0) {
      const int tn = (tt + 2 < TCH) ? (tt + 2) : (TCH - 1);
      xg_n = xgbase[(size_t)tn * G4 + row];
    }

    const f32x4* h4 = (const f32x4*)&h_s[tt & 1][kh * 64];
    float a0 = 0.f, a1 = 0.f, a2 = 0.f, a3 = 0.f;
    #pragma unroll
    for (int kk = 0; kk < 16; ++kk) {
      f32x4 hv = h4[kk];
      a0 = fmaf(w4[kk].x, hv.x, a0);
      a1 = fmaf(w4[kk].y, hv.y, a1);
      a2 = fmaf(w4[kk].z, hv.z, a2);
      a3 = fmaf(w4[kk].w, hv.w, a3);
    }
    const float p = (a0 + a1) + (a2 + a3);
    if (kh == 0) pp[row].x = p + xg;
    else         pp[row].y = p;
    __syncthreads();
    if (tid < HDIM) {
      float2 pi = pp[tid];
      float2 pf = pp[HDIM + tid];
      float2 pg = pp[2 * HDIM + tid];
      float2 po = pp[3 * HDIM + tid];
      float gi = fsig(pi.x + pi.y);
      float gf = fsig(pf.x + pf.y);
      float gg = ftanh(pg.x + pg.y);
      float go = fsig(po.x + po.y);
      c = fmaf(gf, c, gi * gg);
      float h = go * ftanh(c);
      h_s[(tt & 1) ^ 1][tid] = h;
      Hout[(size_t)(b * S_LEN + t0 + tt) * HDIM + tid] = h;
    }
    __syncthreads();
  }
  if (tid < HDIM) c_state[b * HDIM + tid] = c;
}

// ---------------------------------------------------------------------------
// Attention pass 1 (unchanged)
// ---------------------------------------------------------------------------
__global__ __launch_bounds__(128)
void attn1(const float* __restrict__ Hs, const float* __restrict__ attn_w,
           const float* __restrict__ attn_b, const float* __restrict__ v_w,
           const float* __restrict__ v_b, float* __restrict__ logits)
{
  const int b  = blockIdx.x;
  const int tc = blockIdx.y;
  const int j  = threadIdx.x;
  float wreg[HDIM];
  {
    const float4* wr = (const float4*)(attn_w + (size_t)j * HDIM);
    #pragma unroll
    for (int kk = 0; kk < 32; ++kk) {
      float4 v = wr[kk];
      wreg[4*kk+0] = v.x; wreg[4*kk+1] = v.y; wreg[4*kk+2] = v.z; wreg[4*kk+3] = v.w;
    }
  }
  const float ab = attn_b[j];
  const float vw = v_w[j];
  const float vb = v_b[0];
  __shared__ float outs[16][HDIM];
  __shared__ float red[2];
  for (int t8 = 0; t8 < 8; ++t8) {
    const int tbase = tc * 128 + t8 * 16;
    for (int idx = j; idx < 16 * HDIM; idx += 128) {
      int rr = idx >> 7;
      int k  = idx & 127;
      outs[rr][k] = Hs[(size_t)(b * S_LEN + tbase + rr) * HDIM + k];
    }
    __syncthreads();
    for (int rr = 0; rr < 16; ++rr) {
      const float4* o4 = (const float4*)outs[rr];
      float a0 = 0.f, a1 = 0.f, a2 = 0.f, a3 = 0.f;
      #pragma unroll
      for (int kk = 0; kk < 32; ++kk) {
        float4 hv = o4[kk];
        a0 = fmaf(wreg[4*kk+0], hv.x, a0);
        a1 = fmaf(wreg[4*kk+1], hv.y, a1);
        a2 = fmaf(wreg[4*kk+2], hv.z, a2);
        a3 = fmaf(wreg[4*kk+3], hv.w, a3);
      }
      float s = ftanh(((a0 + a1) + (a2 + a3)) + ab) * vw;
      #pragma unroll
      for (int off = 1; off < 64; off <<= 1) s += __shfl_xor(s, off);
      if ((j & 63) == 0) red[j >> 6] = s;
      __syncthreads();
      if (j == 0) logits[b * S_LEN + tbase + rr] = red[0] + red[1] + vb;
      __syncthreads();
    }
  }
}

// ---------------------------------------------------------------------------
// Attention pass 2 (unchanged)
// ---------------------------------------------------------------------------
__global__ __launch_bounds__(128)
void attn2(const float* __restrict__ Hs, const float* __restrict__ logits,
           const float* __restrict__ fc_w, const float* __restrict__ fc_b,
           float* __restrict__ outp)
{
  const int b   = blockIdx.x;
  const int tid = threadIdx.x;
  __shared__ float pbuf[S_LEN];
  __shared__ float red[4];
  __shared__ float ctx_s[HDIM];
  float l0 = logits[b * S_LEN + tid];
  float l1 = logits[b * S_LEN + 128 + tid];
  float l2 = logits[b * S_LEN + 256 + tid];
  float l3 = logits[b * S_LEN + 384 + tid];
  float m = fmaxf(fmaxf(l0, l1), fmaxf(l2, l3));
  #pragma unroll
  for (int off = 1; off < 64; off <<= 1) m = fmaxf(m, __shfl_xor(m, off));
  if ((tid & 63) == 0) red[tid >> 6] = m;
  __syncthreads();
  m = fmaxf(red[0], red[1]);
  float p0 = __expf(l0 - m), p1 = __expf(l1 - m), p2 = __expf(l2 - m), p3 = __expf(l3 - m);
  pbuf[tid] = p0; pbuf[tid + 128] = p1; pbuf[tid + 256] = p2; pbuf[tid + 384] = p3;
  float sum = (p0 + p1) + (p2 + p3);
  #pragma unroll
  for (int off = 1; off < 64; off <<= 1) sum += __shfl_xor(sum, off);
  if ((tid & 63) == 0) red[2 + (tid >> 6)] = sum;
  __syncthreads();
  const float sinv = 1.0f / (red[2] + red[3]);
  float acc = 0.f;
  const float* hp = Hs + (size_t)b * S_LEN * HDIM + tid;
  #pragma unroll 4
  for (int t = 0; t < S_LEN; ++t) acc = fmaf(pbuf[t], hp[(size_t)t * HDIM], acc);
  ctx_s[tid] = acc * sinv;
  __syncthreads();
  if (tid < 7) {
    float a = fc_b[tid];
    const float* fw = fc_w + tid * HDIM;
    #pragma unroll 8
    for (int k = 0; k < HDIM; ++k) a = fmaf(ctx_s[k], fw[k], a);
    outp[b * 7 + tid] = a;
  }
}

// ---------------------------------------------------------------------------
extern "C" void kernel_launch(void* const* d_in, const int* in_sizes, int n_in,
                              void* d_out, int out_size, void* d_ws, size_t ws_size,
                              hipStream_t stream)
{
  const float* x      = (const float*)d_in[0];
  const float* w_ih0  = (const float*)d_in[1];
  const float* w_ih   = (const float*)d_in[2];
  const float* w_hh   = (const float*)d_in[3];
  const float* b_ih   = (const float*)d_in[4];
  const float* b_hh   = (const float*)d_in[5];
  const float* attn_w = (const float*)d_in[6];
  const float* attn_b = (const float*)d_in[7];
  const float* v_w    = (const float*)d_in[8];
  const float* v_b    = (const float*)d_in[9];
  const float* fc_w   = (const float*)d_in[10];
  const float* fc_b   = (const float*)d_in[11];
  float* outp = (float*)d_out;

  const size_t szXG = (size_t)BATCH * TCH * G4;
  const size_t szH  = (size_t)BATCH * S_LEN * HDIM;
  const int    nWih = (NLAYER - 1) * G4 * HDIM;     // 589824
  char* p = (char*)d_ws;
  float* XG = (float*)p;  p += szXG * 4;
  float* H0 = (float*)p;  p += szH * 4;
  float* H1 = (float*)p;  p += szH * 4;
  float* cst = (float*)p; p += (size_t)BATCH * HDIM * 4;
  unsigned short* Whi = (unsigned short*)p; p += (size_t)nWih * 2;
  unsigned short* Wlo = (unsigned short*)p; p += (size_t)nWih * 2;
  float* lg  = XG;  // logits overlap XG: XG dead once the last scan finished
  if ((size_t)(p - (char*)d_ws) > ws_size) return;

  // Pre-split all layers-1..9 input-projection weights into bf16 hi/lo.
  split_w<<<(nWih + 255) / 256, 256, 0, stream>>>(w_ih, Whi, Wlo, nWih);

  for (int l = 0; l < NLAYER; ++l) {
    const float* Ain = (l == 0) ? x : ((l & 1) ? H0 : H1);
    float* Ho = (l & 1) ? H1 : H0;
    const float* bi = b_ih + l * G4;
    const float* bh = b_hh + l * G4;
    const float* Wh = w_hh + (size_t)l * G4 * HDIM;
    for (int cch = 0; cch < NCH; ++cch) {
      int t0 = cch * TCH;
      if (l == 0)
        gemm_xg<27><<<dim3(BATCH * TCH / 64, G4 / 64), 256, 0, stream>>>(x, w_ih0, bi, bh, XG, t0);
      else
        gemm_xg_mfma<<<dim3(BATCH * TCH / 64, G4 / 64), 256, 0, stream>>>(
            Ain, Whi + (size_t)(l - 1) * G4 * HDIM, Wlo + (size_t)(l - 1) * G4 * HDIM,
            bi, bh, XG, t0);
      lstm_scan<<<BATCH, 1024, 0, stream>>>(XG, Wh, Ho, cst, t0);
    }
  }
  const float* Hlast = H1;
  attn1<<<dim3(BATCH, 4), 128, 0, stream>>>(Hlast, attn_w, attn_b, v_w, v_b, lg);
  attn2<<<BATCH, 128, 0, stream>>>(Hlast, lg, fc_w, fc_b, outp);
}